// Round 11
// baseline (1577.008 us; speedup 1.0000x reference)
//
#include <hip/hip_runtime.h>
#include <math.h>

#define BB 32
#define TT 128
#define EE 128
#define HD 128
#define G4 512   // 4*H
#define NV 32000

typedef _Float16 f16x2 __attribute__((ext_vector_type(2)));
typedef _Float16 f16x8 __attribute__((ext_vector_type(8)));
typedef float    f32x4 __attribute__((ext_vector_type(4)));

// ---------------- Kernel A (fused): blocks 0..1999 split Wd, 2000..2511 embed ----------------
__global__ __launch_bounds__(256) void k_prep(
    const int* __restrict__ inputs, const float* __restrict__ emb,
    const float* __restrict__ W0, const float* __restrict__ b0,
    float* __restrict__ Z0x,
    const float* __restrict__ Wd, _Float16* __restrict__ Whi, _Float16* __restrict__ Wlo)
{
    if (blockIdx.x < 2000) {
        if (Whi == nullptr) return;   // small-ws fallback: no split buffers
        const int g = blockIdx.x * 256 + threadIdx.x;
        const int chunk = g >> 6;           // 0..7999
        const int lane = g & 63;
        const int ntile = chunk >> 2;
        const int kstep = chunk & 3;
        const int n = ntile * 16 + (lane & 15);
        const int kb = kstep * 32 + (lane >> 4) * 8;
        _Float16 hi[8], lo[8];
        #pragma unroll
        for (int j = 0; j < 8; ++j) {
            float v = Wd[(size_t)(kb + j) * NV + n];
            hi[j] = (_Float16)v;
            lo[j] = (_Float16)(v - (float)hi[j]);
        }
        *(float4*)&Whi[(size_t)chunk * 512 + lane * 8] = *(const float4*)hi;
        *(float4*)&Wlo[(size_t)chunk * 512 + lane * 8] = *(const float4*)lo;
        return;
    }
    __shared__ float xs[8][EE];
    const int r0 = (blockIdx.x - 2000) * 8;
    const int tid = threadIdx.x;
    for (int i = tid; i < 8 * EE; i += 256) {
        int r = i >> 7, e = i & 127;
        int tok = inputs[r0 + r];
        xs[r][e] = emb[tok * EE + e];
    }
    __syncthreads();
    const int c2 = tid * 2;
    float2 bb2 = *(const float2*)&b0[c2];
    float acc[8][2];
    #pragma unroll
    for (int r = 0; r < 8; ++r) { acc[r][0] = bb2.x; acc[r][1] = bb2.y; }
    for (int e = 0; e < EE; ++e) {
        float2 w = *(const float2*)&W0[e * G4 + c2];
        #pragma unroll
        for (int r = 0; r < 8; ++r) {
            float x = xs[r][e];
            acc[r][0] = fmaf(x, w.x, acc[r][0]);
            acc[r][1] = fmaf(x, w.y, acc[r][1]);
        }
    }
    #pragma unroll
    for (int r = 0; r < 8; ++r) {
        float2 o2; o2.x = acc[r][0]; o2.y = acc[r][1];
        *(float2*)&Z0x[(size_t)(r0 + r) * G4 + c2] = o2;
    }
}

// ---------------- Kernel B: 2-layer LSTM, VGPR+AGPR register-resident weights ----------------
// 32 blocks x 256 threads, launch_bounds(256,1): 256 arch-VGPR budget (proven
// round 8) + 256 AGPRs at 1 wave/SIMD. Thread owns gate columns {tid, tid+256}.
// Weight placement: U0(a,b) + U1(b) = 48 named f16x8 = 192 VGPR;
// U1(a) + W1(a,b) = 192 AGPR via explicit v_accvgpr_write (compiler never
// AGPR-spills on its own - round 8 went to scratch). Unified 419 < 450 (m08).
#define REPEAT16(X) X(0) X(1) X(2) X(3) X(4) X(5) X(6) X(7) \
                    X(8) X(9) X(10) X(11) X(12) X(13) X(14) X(15)

#define SV2(H, J) __builtin_shufflevector(H, H, 2*(J), 2*(J)+1)
#define AREAD(D, S)  asm("v_accvgpr_read_b32 %0, %1" : "=v"(D) : "a"(S))
#define AWRITE(D, S) asm("v_accvgpr_write_b32 %0, %1" : "=a"(D) : "v"(S))
#define FD2(ACC, HP, WP) ACC = __builtin_amdgcn_fdot2(HP, WP, ACC, false)

#define DOT8V(ACC, H, V) do { \
    FD2(ACC, SV2(H,0), SV2(V,0)); FD2(ACC, SV2(H,1), SV2(V,1)); \
    FD2(ACC, SV2(H,2), SV2(V,2)); FD2(ACC, SV2(H,3), SV2(V,3)); } while (0)

#define DOT8A(ACC, H, P) do { \
    f16x2 _w0, _w1, _w2, _w3; \
    AREAD(_w0, P##_0); AREAD(_w1, P##_1); AREAD(_w2, P##_2); AREAD(_w3, P##_3); \
    FD2(ACC, SV2(H,0), _w0); FD2(ACC, SV2(H,1), _w1); \
    FD2(ACC, SV2(H,2), _w2); FD2(ACC, SV2(H,3), _w3); } while (0)

#define LD8(VAR, MAT, COL, I) do { f16x8 _v; \
    _v[0] = (_Float16)MAT[((I)*8 + 0) * G4 + (COL)]; \
    _v[1] = (_Float16)MAT[((I)*8 + 1) * G4 + (COL)]; \
    _v[2] = (_Float16)MAT[((I)*8 + 2) * G4 + (COL)]; \
    _v[3] = (_Float16)MAT[((I)*8 + 3) * G4 + (COL)]; \
    _v[4] = (_Float16)MAT[((I)*8 + 4) * G4 + (COL)]; \
    _v[5] = (_Float16)MAT[((I)*8 + 5) * G4 + (COL)]; \
    _v[6] = (_Float16)MAT[((I)*8 + 6) * G4 + (COL)]; \
    _v[7] = (_Float16)MAT[((I)*8 + 7) * G4 + (COL)]; \
    VAR = _v; } while (0)

#define LD8A(P, MAT, COL, I) do { f16x8 _v; \
    _v[0] = (_Float16)MAT[((I)*8 + 0) * G4 + (COL)]; \
    _v[1] = (_Float16)MAT[((I)*8 + 1) * G4 + (COL)]; \
    _v[2] = (_Float16)MAT[((I)*8 + 2) * G4 + (COL)]; \
    _v[3] = (_Float16)MAT[((I)*8 + 3) * G4 + (COL)]; \
    _v[4] = (_Float16)MAT[((I)*8 + 4) * G4 + (COL)]; \
    _v[5] = (_Float16)MAT[((I)*8 + 5) * G4 + (COL)]; \
    _v[6] = (_Float16)MAT[((I)*8 + 6) * G4 + (COL)]; \
    _v[7] = (_Float16)MAT[((I)*8 + 7) * G4 + (COL)]; \
    AWRITE(P##_0, SV2(_v,0)); AWRITE(P##_1, SV2(_v,1)); \
    AWRITE(P##_2, SV2(_v,2)); AWRITE(P##_3, SV2(_v,3)); } while (0)

#define DECLW(i) f16x8 u0a_##i, u0b_##i, u1b_##i; \
    f16x2 u1a_##i##_0, u1a_##i##_1, u1a_##i##_2, u1a_##i##_3, \
          w1a_##i##_0, w1a_##i##_1, w1a_##i##_2, w1a_##i##_3, \
          w1b_##i##_0, w1b_##i##_1, w1b_##i##_2, w1b_##i##_3;

#define LOADW(i) \
    LD8(u0a_##i, U0, ca, i); LD8(u0b_##i, U0, cb, i); LD8(u1b_##i, U1, cb, i); \
    LD8A(u1a_##i, U1, ca, i); LD8A(w1a_##i, W1, ca, i); LD8A(w1b_##i, W1, cb, i);

#define PHASEA(i) { f16x8 h0c = h0q[i]; \
    DOT8V((((i)&1) ? z0a2 : z0a1), h0c, u0a_##i); \
    DOT8V((((i)&1) ? z0b2 : z0b1), h0c, u0b_##i); \
    f16x8 h1c = h1q[i]; \
    DOT8A((((i)&1) ? zua2 : zua1), h1c, u1a_##i); \
    DOT8V((((i)&1) ? zub2 : zub1), h1c, u1b_##i); }

#define PHASEC(i) { f16x8 h0c = h0q[i]; \
    DOT8A((((i)&1) ? z1a2 : z1a1), h0c, w1a_##i); \
    DOT8A((((i)&1) ? z1b2 : z1b1), h0c, w1b_##i); }

__global__ __launch_bounds__(256, 1) void k_lstm_f4(
    const float* __restrict__ Z0x,
    const float* __restrict__ U0, const float* __restrict__ W1,
    const float* __restrict__ U1, const float* __restrict__ b1,
    float* __restrict__ y)
{
    const int b = blockIdx.x;
    const int tid = threadIdx.x;
    const int ca = tid;          // gate column A
    const int cb = tid + 256;    // gate column B

    __shared__ _Float16 h0p[HD];
    __shared__ _Float16 h1p[HD];
    __shared__ float zb[G4];

    REPEAT16(DECLW)
    REPEAT16(LOADW)

    const float b1a = b1[ca], b1b = b1[cb];
    const float* __restrict__ zrow = Z0x + (size_t)b * TT * G4;

    float c0 = 0.f, c1 = 0.f;   // cell states (threads 0..127)
    if (tid < HD) { h0p[tid] = (_Float16)0.f; h1p[tid] = (_Float16)0.f; }
    __syncthreads();

    const f16x8* h0q = (const f16x8*)h0p;   // 16 chunks of 8 halves
    const f16x8* h1q = (const f16x8*)h1p;

    for (int t = 0; t < TT; ++t) {
        // ---- phase A: z0 = Z0x[b,t] + h0@U0 (cols a,b); zu = h1@U1 ----
        float z0a1 = zrow[(size_t)t * G4 + ca], z0a2 = 0.f;
        float z0b1 = zrow[(size_t)t * G4 + cb], z0b2 = 0.f;
        float zua1 = 0.f, zua2 = 0.f, zub1 = 0.f, zub2 = 0.f;
        REPEAT16(PHASEA)
        zb[ca] = z0a1 + z0a2;
        zb[cb] = z0b1 + z0b2;
        const float zuA = zua1 + zua2;     // this thread's own U1 dots, kept in regs
        const float zuB = zub1 + zub2;
        __syncthreads();

        // ---- phase B: layer-0 gates -> h0_t ----
        if (tid < HD) {
            float zi = zb[tid], zf = zb[HD + tid], zc = zb[2 * HD + tid], zo = zb[3 * HD + tid];
            float ig = 1.f / (1.f + expf(-zi));
            float fg = 1.f / (1.f + expf(-zf));
            float og = 1.f / (1.f + expf(-zo));
            c0 = fg * c0 + ig * tanhf(zc);
            h0p[tid] = (_Float16)(og * tanhf(c0));
        }
        __syncthreads();

        // ---- phase C: z1 = b1 + zu + h0_t@W1 ----
        float z1a1 = b1a + zuA, z1a2 = 0.f;
        float z1b1 = b1b + zuB, z1b2 = 0.f;
        REPEAT16(PHASEC)
        zb[ca] = z1a1 + z1a2;
        zb[cb] = z1b1 + z1b2;
        __syncthreads();

        // ---- phase D: layer-1 gates -> h1_t, y ----
        if (tid < HD) {
            float zi = zb[tid], zf = zb[HD + tid], zc = zb[2 * HD + tid], zo = zb[3 * HD + tid];
            float ig = 1.f / (1.f + expf(-zi));
            float fg = 1.f / (1.f + expf(-zf));
            float og = 1.f / (1.f + expf(-zo));
            c1 = fg * c1 + ig * tanhf(zc);
            float hn = og * tanhf(c1);
            h1p[tid] = (_Float16)hn;
            y[(size_t)(b * TT + t) * HD + tid] = hn;
        }
        __syncthreads();
    }
}

// ---------------- Prep: split y into f16 hi/lo, MFMA-fragment-packed ----------------
__global__ __launch_bounds__(256) void k_ysplit(
    const float* __restrict__ y, _Float16* __restrict__ yhi, _Float16* __restrict__ ylo)
{
    const int g = blockIdx.x * 256 + threadIdx.x;
    const int chunk = g >> 6;           // 0..1023
    const int lane = g & 63;
    const int mtile = chunk >> 2;
    const int kstep = chunk & 3;
    const int row = mtile * 16 + (lane & 15);
    const int kb = kstep * 32 + (lane >> 4) * 8;
    _Float16 hi[8], lo[8];
    #pragma unroll
    for (int j = 0; j < 8; ++j) {
        float v = y[(size_t)row * HD + kb + j];
        hi[j] = (_Float16)v;
        lo[j] = (_Float16)(v - (float)hi[j]);
    }
    *(float4*)&yhi[(size_t)chunk * 512 + lane * 8] = *(const float4*)hi;
    *(float4*)&ylo[(size_t)chunk * 512 + lane * 8] = *(const float4*)lo;
}

// ---------------- Kernel C (MFMA): out = y @ Wd + bd via f16 hi/lo split ----------------
// (round-9 version, direct scatter stores — LDS epilogue regressed in R10)
__global__ __launch_bounds__(256) void k_dense_mfma(
    const _Float16* __restrict__ yhi, const _Float16* __restrict__ ylo,
    const _Float16* __restrict__ Whi, const _Float16* __restrict__ Wlo,
    const float* __restrict__ bd, float* __restrict__ out)
{
    const int tid = threadIdx.x;
    const int w = tid >> 6;
    const int lane = tid & 63;
    const int mtile = blockIdx.x * 4 + w;
    const int nt0 = blockIdx.y * 20;

    f16x8 Ah[4], Al[4];
    #pragma unroll
    for (int k = 0; k < 4; ++k) {
        Ah[k] = *(const f16x8*)&yhi[(size_t)(mtile * 4 + k) * 512 + lane * 8];
        Al[k] = *(const f16x8*)&ylo[(size_t)(mtile * 4 + k) * 512 + lane * 8];
    }

    const int m0 = mtile * 16;
    const int r0 = (lane >> 4) * 4;          // C/D row group (m89 mapping)

    for (int nt = 0; nt < 20; ++nt) {
        const int ntile = nt0 + nt;
        const size_t cbb = (size_t)ntile * 4 * 512 + lane * 8;
        f16x8 Bh[4], Bl[4];
        #pragma unroll
        for (int k = 0; k < 4; ++k) {
            Bh[k] = *(const f16x8*)&Whi[cbb + k * 512];
            Bl[k] = *(const f16x8*)&Wlo[cbb + k * 512];
        }
        f32x4 acc0 = {0.f, 0.f, 0.f, 0.f};
        f32x4 acc1 = {0.f, 0.f, 0.f, 0.f};
        #pragma unroll
        for (int k = 0; k < 4; ++k) {
            acc0 = __builtin_amdgcn_mfma_f32_16x16x32_f16(Ah[k], Bh[k], acc0, 0, 0, 0);
            acc1 = __builtin_amdgcn_mfma_f32_16x16x32_f16(Ah[k], Bl[k], acc1, 0, 0, 0);
            acc1 = __builtin_amdgcn_mfma_f32_16x16x32_f16(Al[k], Bh[k], acc1, 0, 0, 0);
        }
        const int col = ntile * 16 + (lane & 15);
        const float bias = bd[col];
        #pragma unroll
        for (int reg = 0; reg < 4; ++reg) {
            out[(size_t)(m0 + r0 + reg) * NV + col] = acc0[reg] + acc1[reg] + bias;
        }
    }
}

// ---------------- Kernel C (fallback, fp32 vector) ----------------
__global__ __launch_bounds__(256) void k_dense(
    const float* __restrict__ y, const float* __restrict__ Wd,
    const float* __restrict__ bd, float* __restrict__ out)
{
    __shared__ float ys[64 * HD];
    const int r0 = blockIdx.x * 64;
    const int v0 = blockIdx.y * 128;
    const int tid = threadIdx.x;
    for (int idx = tid; idx < 64 * HD; idx += 256) ys[idx] = y[(size_t)r0 * HD + idx];
    __syncthreads();
    const int tx = tid & 31;
    const int ty = tid >> 5;
    const int v = v0 + tx * 4;
    float4 bd4 = *(const float4*)&bd[v];
    float acc[8][4] = {};
    const float* yrow = &ys[(ty * 8) * HD];
    #pragma unroll 4
    for (int e = 0; e < HD; ++e) {
        float4 wv = *(const float4*)&Wd[(size_t)e * NV + v];
        #pragma unroll
        for (int j = 0; j < 8; ++j) {
            float yv = yrow[j * HD + e];
            acc[j][0] = fmaf(yv, wv.x, acc[j][0]);
            acc[j][1] = fmaf(yv, wv.y, acc[j][1]);
            acc[j][2] = fmaf(yv, wv.z, acc[j][2]);
            acc[j][3] = fmaf(yv, wv.w, acc[j][3]);
        }
    }
    #pragma unroll
    for (int j = 0; j < 8; ++j) {
        int rr = r0 + ty * 8 + j;
        float4 o4;
        o4.x = acc[j][0] + bd4.x;
        o4.y = acc[j][1] + bd4.y;
        o4.z = acc[j][2] + bd4.z;
        o4.w = acc[j][3] + bd4.w;
        *(float4*)&out[(size_t)rr * NV + v] = o4;
    }
}

extern "C" void kernel_launch(void* const* d_in, const int* in_sizes, int n_in,
                              void* d_out, int out_size, void* d_ws, size_t ws_size,
                              hipStream_t stream)
{
    const int*   inputs = (const int*)  d_in[0];
    const float* emb    = (const float*)d_in[1];
    const float* W0     = (const float*)d_in[2];
    const float* U0     = (const float*)d_in[3];
    const float* b0     = (const float*)d_in[4];
    const float* W1     = (const float*)d_in[5];
    const float* U1     = (const float*)d_in[6];
    const float* b1     = (const float*)d_in[7];
    const float* Wd     = (const float*)d_in[8];
    const float* bd     = (const float*)d_in[9];
    float* out = (float*)d_out;

    // ws layout (MFMA path): Z0x 8MB | yy 2MB | Whi 8MB | Wlo 8MB | yhi 1MB | ylo 1MB
    const size_t Z0X_B = (size_t)8 * 1024 * 1024;
    const size_t YY_B  = (size_t)2 * 1024 * 1024;
    const size_t WSP_B = (size_t)8000 * 512 * 2;        // 8,192,000
    const size_t YSP_B = (size_t)1024 * 512 * 2;        // 1,048,576
    const size_t NEED  = Z0X_B + YY_B + 2 * WSP_B + 2 * YSP_B + 4096;

    char* ws = (char*)d_ws;

    if (ws_size >= NEED) {
        float*     Z0x = (float*)ws;
        float*     yy  = (float*)(ws + Z0X_B);
        _Float16*  Whi = (_Float16*)(ws + Z0X_B + YY_B);
        _Float16*  Wlo = (_Float16*)(ws + Z0X_B + YY_B + WSP_B);
        _Float16*  yhi = (_Float16*)(ws + Z0X_B + YY_B + 2 * WSP_B);
        _Float16*  ylo = (_Float16*)(ws + Z0X_B + YY_B + 2 * WSP_B + YSP_B);

        k_prep<<<2512, 256, 0, stream>>>(inputs, emb, W0, b0, Z0x, Wd, Whi, Wlo);
        k_lstm_f4<<<BB, 256, 0, stream>>>(Z0x, U0, W1, U1, b1, yy);
        k_ysplit<<<256, 256, 0, stream>>>(yy, yhi, ylo);
        k_dense_mfma<<<dim3(64, 100), 256, 0, stream>>>(yhi, ylo, Whi, Wlo, bd, out);
    } else {
        // small-ws fallback: Z0x in d_out tail, yy in ws, fp32 dense
        float* yy = (float*)ws;
        size_t out_bytes = (size_t)out_size * sizeof(float);
        float* Z0x = (float*)((char*)d_out + out_bytes - Z0X_B);

        k_prep<<<2512, 256, 0, stream>>>(inputs, emb, W0, b0, Z0x,
                                         Wd, nullptr, nullptr);
        k_lstm_f4<<<BB, 256, 0, stream>>>(Z0x, U0, W1, U1, b1, yy);
        k_dense<<<dim3(64, 250), 256, 0, stream>>>(yy, Wd, bd, out);
    }
}

// Round 13
// 606.793 us; speedup vs baseline: 2.5989x; 2.5989x over previous
//
#include <hip/hip_runtime.h>
#include <math.h>

#define BB 32
#define TT 128
#define EE 128
#define HD 128
#define G4 512   // 4*H
#define NV 32000

typedef _Float16 f16x2  __attribute__((ext_vector_type(2)));
typedef _Float16 f16x4v __attribute__((ext_vector_type(4)));
typedef _Float16 f16x8  __attribute__((ext_vector_type(8)));
typedef float    f32x4  __attribute__((ext_vector_type(4)));

// ---------------- Kernel A (fused): blocks 0..1999 split Wd, 2000..2511 embed ----------------
__global__ __launch_bounds__(256) void k_prep(
    const int* __restrict__ inputs, const float* __restrict__ emb,
    const float* __restrict__ W0, const float* __restrict__ b0,
    float* __restrict__ Z0x,
    const float* __restrict__ Wd, _Float16* __restrict__ Whi, _Float16* __restrict__ Wlo)
{
    if (blockIdx.x < 2000) {
        if (Whi == nullptr) return;   // small-ws fallback: no split buffers
        const int g = blockIdx.x * 256 + threadIdx.x;
        const int chunk = g >> 6;           // 0..7999
        const int lane = g & 63;
        const int ntile = chunk >> 2;
        const int kstep = chunk & 3;
        const int n = ntile * 16 + (lane & 15);
        const int kb = kstep * 32 + (lane >> 4) * 8;
        _Float16 hi[8], lo[8];
        #pragma unroll
        for (int j = 0; j < 8; ++j) {
            float v = Wd[(size_t)(kb + j) * NV + n];
            hi[j] = (_Float16)v;
            lo[j] = (_Float16)(v - (float)hi[j]);
        }
        *(float4*)&Whi[(size_t)chunk * 512 + lane * 8] = *(const float4*)hi;
        *(float4*)&Wlo[(size_t)chunk * 512 + lane * 8] = *(const float4*)lo;
        return;
    }
    __shared__ float xs[8][EE];
    const int r0 = (blockIdx.x - 2000) * 8;
    const int tid = threadIdx.x;
    for (int i = tid; i < 8 * EE; i += 256) {
        int r = i >> 7, e = i & 127;
        int tok = inputs[r0 + r];
        xs[r][e] = emb[tok * EE + e];
    }
    __syncthreads();
    const int c2 = tid * 2;
    float2 bb2 = *(const float2*)&b0[c2];
    float acc[8][2];
    #pragma unroll
    for (int r = 0; r < 8; ++r) { acc[r][0] = bb2.x; acc[r][1] = bb2.y; }
    for (int e = 0; e < EE; ++e) {
        float2 w = *(const float2*)&W0[e * G4 + c2];
        #pragma unroll
        for (int r = 0; r < 8; ++r) {
            float x = xs[r][e];
            acc[r][0] = fmaf(x, w.x, acc[r][0]);
            acc[r][1] = fmaf(x, w.y, acc[r][1]);
        }
    }
    #pragma unroll
    for (int r = 0; r < 8; ++r) {
        float2 o2; o2.x = acc[r][0]; o2.y = acc[r][1];
        *(float2*)&Z0x[(size_t)(r0 + r) * G4 + c2] = o2;
    }
}

// ---------------- Kernel B: 2-layer LSTM via MFMA recurrence ----------------
// 4 blocks x 256 thr (4 waves, 1 wave/SIMD). Block owns 8 batches (rows 8-15 of
// the 16-row MFMA tile stay zero). Wave owns 128 gate columns. Weights as MFMA
// B-fragments: U0 -> ~128 VGPR; W1,U1 -> 256 AGPR pinned by empty-asm "+a".
// MFMA via INTRINSIC (compiler handles all hazard nops — round-12's raw asm
// had none, which corrupted results). Intrinsic operands are AV-class, so
// AGPR-pinned B fragments are consumed directly, no accvgpr_read bounce.
__device__ __forceinline__ float sigf(float x) {
    return __builtin_amdgcn_rcpf(1.f + __builtin_amdgcn_exp2f(x * -1.44269504088896f));
}
__device__ __forceinline__ float tanh_f(float x) {
    return 1.f - 2.f * __builtin_amdgcn_rcpf(1.f + __builtin_amdgcn_exp2f(x * 2.88539008177793f));
}
__device__ __forceinline__ f16x8 ldfrag(const float* __restrict__ M, int col, int k0) {
    f16x8 v;
    #pragma unroll
    for (int j = 0; j < 8; ++j) v[j] = (_Float16)M[(size_t)(k0 + j) * G4 + col];
    return v;
}

#define REP8(X) X(0) X(1) X(2) X(3) X(4) X(5) X(6) X(7)

#define MFMA(acc, a, b) acc = __builtin_amdgcn_mfma_f32_16x16x32_f16(a, b, acc, 0, 0, 0)

#define DECLF(n) f16x8 u0_##n##_0, u0_##n##_1, u0_##n##_2, u0_##n##_3, \
                       w1_##n##_0, w1_##n##_1, w1_##n##_2, w1_##n##_3, \
                       u1_##n##_0, u1_##n##_1, u1_##n##_2, u1_##n##_3;

#define LOADF(n) { const int cn = wc0 + (n) * 16 + lo16; \
    u0_##n##_0 = ldfrag(U0, cn, khi);      u0_##n##_1 = ldfrag(U0, cn, 32 + khi); \
    u0_##n##_2 = ldfrag(U0, cn, 64 + khi); u0_##n##_3 = ldfrag(U0, cn, 96 + khi); \
    w1_##n##_0 = ldfrag(W1, cn, khi);      w1_##n##_1 = ldfrag(W1, cn, 32 + khi); \
    w1_##n##_2 = ldfrag(W1, cn, 64 + khi); w1_##n##_3 = ldfrag(W1, cn, 96 + khi); \
    asm("" : "+a"(w1_##n##_0), "+a"(w1_##n##_1), "+a"(w1_##n##_2), "+a"(w1_##n##_3)); \
    u1_##n##_0 = ldfrag(U1, cn, khi);      u1_##n##_1 = ldfrag(U1, cn, 32 + khi); \
    u1_##n##_2 = ldfrag(U1, cn, 64 + khi); u1_##n##_3 = ldfrag(U1, cn, 96 + khi); \
    asm("" : "+a"(u1_##n##_0), "+a"(u1_##n##_1), "+a"(u1_##n##_2), "+a"(u1_##n##_3)); }

#define PA(n) { f32x4 acc = {0.f, 0.f, 0.f, 0.f}; \
    MFMA(acc, ha0, u0_##n##_0); MFMA(acc, ha1, u0_##n##_1); \
    MFMA(acc, ha2, u0_##n##_2); MFMA(acc, ha3, u0_##n##_3); \
    if (lane < 32) { const int cw = wc0 + (n) * 16 + lo16; const int br = (lane >> 4) * 4; \
        zbuf[br + 0][cw] = acc[0]; zbuf[br + 1][cw] = acc[1]; \
        zbuf[br + 2][cw] = acc[2]; zbuf[br + 3][cw] = acc[3]; } }

#define PC(n) { f32x4 acc = {0.f, 0.f, 0.f, 0.f}; \
    MFMA(acc, ha0, w1_##n##_0); MFMA(acc, ha1, w1_##n##_1); \
    MFMA(acc, ha2, w1_##n##_2); MFMA(acc, ha3, w1_##n##_3); \
    MFMA(acc, hb0, u1_##n##_0); MFMA(acc, hb1, u1_##n##_1); \
    MFMA(acc, hb2, u1_##n##_2); MFMA(acc, hb3, u1_##n##_3); \
    if (lane < 32) { const int cw = wc0 + (n) * 16 + lo16; const int br = (lane >> 4) * 4; \
        zbuf[br + 0][cw] = acc[0]; zbuf[br + 1][cw] = acc[1]; \
        zbuf[br + 2][cw] = acc[2]; zbuf[br + 3][cw] = acc[3]; } }

#define GT0(K, ZI, ZF, ZC, ZO) { \
    float ig = sigf(ZI), fg = sigf(ZF), og = sigf(ZO), gg = tanh_f(ZC); \
    float cn = fg * c0v[K] + ig * gg; c0v[K] = cn; hv[K] = (_Float16)(og * tanh_f(cn)); }

#define GT1(K, ZI, ZF, ZC, ZO, YO) { \
    float ig = sigf(ZI), fg = sigf(ZF), og = sigf(ZO), gg = tanh_f(ZC); \
    float cn = fg * c1v[K] + ig * gg; c1v[K] = cn; float hn = og * tanh_f(cn); \
    hv[K] = (_Float16)hn; YO = hn; }

__global__ __launch_bounds__(256, 1) void k_lstm_m(
    const float* __restrict__ Z0x,
    const float* __restrict__ U0, const float* __restrict__ W1,
    const float* __restrict__ U1, const float* __restrict__ b1,
    float* __restrict__ y)
{
    const int tid  = threadIdx.x;
    const int lane = tid & 63;
    const int wc0  = (tid >> 6) * 128;     // wave's column base
    const int lo16 = lane & 15;
    const int khi  = (lane >> 4) * 8;
    const int B0   = blockIdx.x * 8;       // batch base

    __shared__ float     zbuf[8][516];     // z scores, +4 pad
    __shared__ _Float16  h0p[16][136];     // h0, rows 8-15 stay zero, +8 pad
    __shared__ _Float16  h1p[16][136];

    REP8(DECLF)
    REP8(LOADF)

    // gate-thread mapping: bq = batch, 4 h-units per thread
    const int bq  = tid >> 5;              // 0..7
    const int h0i = (tid & 31) * 4;        // 0..124
    const float* zx_base = Z0x + ((size_t)(B0 + bq) * TT) * G4;
    float*       y_base  = y   + ((size_t)(B0 + bq) * TT) * HD + h0i;

    const float4 b1_i = *(const float4*)&b1[0 * 128 + h0i];
    const float4 b1_f = *(const float4*)&b1[1 * 128 + h0i];
    const float4 b1_c = *(const float4*)&b1[2 * 128 + h0i];
    const float4 b1_o = *(const float4*)&b1[3 * 128 + h0i];

    for (int i = tid; i < 16 * 136; i += 256) {
        ((_Float16*)h0p)[i] = (_Float16)0.f;
        ((_Float16*)h1p)[i] = (_Float16)0.f;
    }
    f32x4 c0v = {0.f, 0.f, 0.f, 0.f};
    f32x4 c1v = {0.f, 0.f, 0.f, 0.f};
    __syncthreads();

    for (int t = 0; t < TT; ++t) {
        // prefetch Z0x gate rows (consumed in gates-0, hidden under MFMA)
        const float* zx = zx_base + (size_t)t * G4;
        const float4 x_i = *(const float4*)&zx[0 * 128 + h0i];
        const float4 x_f = *(const float4*)&zx[1 * 128 + h0i];
        const float4 x_c = *(const float4*)&zx[2 * 128 + h0i];
        const float4 x_o = *(const float4*)&zx[3 * 128 + h0i];

        // ---- phase A: zbuf = U0^T h0_{t-1} ----
        {
            f16x8 ha0 = *(const f16x8*)&h0p[lo16][khi];
            f16x8 ha1 = *(const f16x8*)&h0p[lo16][32 + khi];
            f16x8 ha2 = *(const f16x8*)&h0p[lo16][64 + khi];
            f16x8 ha3 = *(const f16x8*)&h0p[lo16][96 + khi];
            REP8(PA)
        }
        __syncthreads();

        // ---- phase B: layer-0 gates -> h0_t ----
        {
            const float4 zi4 = *(const float4*)&zbuf[bq][0 * 128 + h0i];
            const float4 zf4 = *(const float4*)&zbuf[bq][1 * 128 + h0i];
            const float4 zc4 = *(const float4*)&zbuf[bq][2 * 128 + h0i];
            const float4 zo4 = *(const float4*)&zbuf[bq][3 * 128 + h0i];
            f16x4v hv;
            GT0(0, zi4.x + x_i.x, zf4.x + x_f.x, zc4.x + x_c.x, zo4.x + x_o.x)
            GT0(1, zi4.y + x_i.y, zf4.y + x_f.y, zc4.y + x_c.y, zo4.y + x_o.y)
            GT0(2, zi4.z + x_i.z, zf4.z + x_f.z, zc4.z + x_c.z, zo4.z + x_o.z)
            GT0(3, zi4.w + x_i.w, zf4.w + x_f.w, zc4.w + x_c.w, zo4.w + x_o.w)
            *(f16x4v*)&h0p[bq][h0i] = hv;
        }
        __syncthreads();

        // ---- phase C: zbuf = W1^T h0_t + U1^T h1_{t-1} ----
        {
            f16x8 ha0 = *(const f16x8*)&h0p[lo16][khi];
            f16x8 ha1 = *(const f16x8*)&h0p[lo16][32 + khi];
            f16x8 ha2 = *(const f16x8*)&h0p[lo16][64 + khi];
            f16x8 ha3 = *(const f16x8*)&h0p[lo16][96 + khi];
            f16x8 hb0 = *(const f16x8*)&h1p[lo16][khi];
            f16x8 hb1 = *(const f16x8*)&h1p[lo16][32 + khi];
            f16x8 hb2 = *(const f16x8*)&h1p[lo16][64 + khi];
            f16x8 hb3 = *(const f16x8*)&h1p[lo16][96 + khi];
            REP8(PC)
        }
        __syncthreads();

        // ---- phase D: layer-1 gates -> h1_t, y ----
        {
            const float4 zi4 = *(const float4*)&zbuf[bq][0 * 128 + h0i];
            const float4 zf4 = *(const float4*)&zbuf[bq][1 * 128 + h0i];
            const float4 zc4 = *(const float4*)&zbuf[bq][2 * 128 + h0i];
            const float4 zo4 = *(const float4*)&zbuf[bq][3 * 128 + h0i];
            f16x4v hv; float4 yv;
            GT1(0, zi4.x + b1_i.x, zf4.x + b1_f.x, zc4.x + b1_c.x, zo4.x + b1_o.x, yv.x)
            GT1(1, zi4.y + b1_i.y, zf4.y + b1_f.y, zc4.y + b1_c.y, zo4.y + b1_o.y, yv.y)
            GT1(2, zi4.z + b1_i.z, zf4.z + b1_f.z, zc4.z + b1_c.z, zo4.z + b1_o.z, yv.z)
            GT1(3, zi4.w + b1_i.w, zf4.w + b1_f.w, zc4.w + b1_c.w, zo4.w + b1_o.w, yv.w)
            *(f16x4v*)&h1p[bq][h0i] = hv;
            *(float4*)(y_base + (size_t)t * HD) = yv;
        }
        __syncthreads();
    }
}

// ---------------- Prep: split y into f16 hi/lo, MFMA-fragment-packed ----------------
__global__ __launch_bounds__(256) void k_ysplit(
    const float* __restrict__ y, _Float16* __restrict__ yhi, _Float16* __restrict__ ylo)
{
    const int g = blockIdx.x * 256 + threadIdx.x;
    const int chunk = g >> 6;           // 0..1023
    const int lane = g & 63;
    const int mtile = chunk >> 2;
    const int kstep = chunk & 3;
    const int row = mtile * 16 + (lane & 15);
    const int kb = kstep * 32 + (lane >> 4) * 8;
    _Float16 hi[8], lo[8];
    #pragma unroll
    for (int j = 0; j < 8; ++j) {
        float v = y[(size_t)row * HD + kb + j];
        hi[j] = (_Float16)v;
        lo[j] = (_Float16)(v - (float)hi[j]);
    }
    *(float4*)&yhi[(size_t)chunk * 512 + lane * 8] = *(const float4*)hi;
    *(float4*)&ylo[(size_t)chunk * 512 + lane * 8] = *(const float4*)lo;
}

// ---------------- Kernel C (MFMA): out = y @ Wd + bd via f16 hi/lo split ----------------
__global__ __launch_bounds__(256) void k_dense_mfma(
    const _Float16* __restrict__ yhi, const _Float16* __restrict__ ylo,
    const _Float16* __restrict__ Whi, const _Float16* __restrict__ Wlo,
    const float* __restrict__ bd, float* __restrict__ out)
{
    const int tid = threadIdx.x;
    const int w = tid >> 6;
    const int lane = tid & 63;
    const int mtile = blockIdx.x * 4 + w;
    const int nt0 = blockIdx.y * 20;

    f16x8 Ah[4], Al[4];
    #pragma unroll
    for (int k = 0; k < 4; ++k) {
        Ah[k] = *(const f16x8*)&yhi[(size_t)(mtile * 4 + k) * 512 + lane * 8];
        Al[k] = *(const f16x8*)&ylo[(size_t)(mtile * 4 + k) * 512 + lane * 8];
    }

    const int m0 = mtile * 16;
    const int r0 = (lane >> 4) * 4;          // C/D row group (m89 mapping)

    for (int nt = 0; nt < 20; ++nt) {
        const int ntile = nt0 + nt;
        const size_t cbb = (size_t)ntile * 4 * 512 + lane * 8;
        f16x8 Bh[4], Bl[4];
        #pragma unroll
        for (int k = 0; k < 4; ++k) {
            Bh[k] = *(const f16x8*)&Whi[cbb + k * 512];
            Bl[k] = *(const f16x8*)&Wlo[cbb + k * 512];
        }
        f32x4 acc0 = {0.f, 0.f, 0.f, 0.f};
        f32x4 acc1 = {0.f, 0.f, 0.f, 0.f};
        #pragma unroll
        for (int k = 0; k < 4; ++k) {
            acc0 = __builtin_amdgcn_mfma_f32_16x16x32_f16(Ah[k], Bh[k], acc0, 0, 0, 0);
            acc1 = __builtin_amdgcn_mfma_f32_16x16x32_f16(Ah[k], Bl[k], acc1, 0, 0, 0);
            acc1 = __builtin_amdgcn_mfma_f32_16x16x32_f16(Al[k], Bh[k], acc1, 0, 0, 0);
        }
        const int col = ntile * 16 + (lane & 15);
        const float bias = bd[col];
        #pragma unroll
        for (int reg = 0; reg < 4; ++reg) {
            out[(size_t)(m0 + r0 + reg) * NV + col] = acc0[reg] + acc1[reg] + bias;
        }
    }
}

// ---------------- Kernel C (fallback, fp32 vector) ----------------
__global__ __launch_bounds__(256) void k_dense(
    const float* __restrict__ y, const float* __restrict__ Wd,
    const float* __restrict__ bd, float* __restrict__ out)
{
    __shared__ float ys[64 * HD];
    const int r0 = blockIdx.x * 64;
    const int v0 = blockIdx.y * 128;
    const int tid = threadIdx.x;
    for (int idx = tid; idx < 64 * HD; idx += 256) ys[idx] = y[(size_t)r0 * HD + idx];
    __syncthreads();
    const int tx = tid & 31;
    const int ty = tid >> 5;
    const int v = v0 + tx * 4;
    float4 bd4 = *(const float4*)&bd[v];
    float acc[8][4] = {};
    const float* yrow = &ys[(ty * 8) * HD];
    #pragma unroll 4
    for (int e = 0; e < HD; ++e) {
        float4 wv = *(const float4*)&Wd[(size_t)e * NV + v];
        #pragma unroll
        for (int j = 0; j < 8; ++j) {
            float yv = yrow[j * HD + e];
            acc[j][0] = fmaf(yv, wv.x, acc[j][0]);
            acc[j][1] = fmaf(yv, wv.y, acc[j][1]);
            acc[j][2] = fmaf(yv, wv.z, acc[j][2]);
            acc[j][3] = fmaf(yv, wv.w, acc[j][3]);
        }
    }
    #pragma unroll
    for (int j = 0; j < 8; ++j) {
        int rr = r0 + ty * 8 + j;
        float4 o4;
        o4.x = acc[j][0] + bd4.x;
        o4.y = acc[j][1] + bd4.y;
        o4.z = acc[j][2] + bd4.z;
        o4.w = acc[j][3] + bd4.w;
        *(float4*)&out[(size_t)rr * NV + v] = o4;
    }
}

extern "C" void kernel_launch(void* const* d_in, const int* in_sizes, int n_in,
                              void* d_out, int out_size, void* d_ws, size_t ws_size,
                              hipStream_t stream)
{
    const int*   inputs = (const int*)  d_in[0];
    const float* emb    = (const float*)d_in[1];
    const float* W0     = (const float*)d_in[2];
    const float* U0     = (const float*)d_in[3];
    const float* b0     = (const float*)d_in[4];
    const float* W1     = (const float*)d_in[5];
    const float* U1     = (const float*)d_in[6];
    const float* b1     = (const float*)d_in[7];
    const float* Wd     = (const float*)d_in[8];
    const float* bd     = (const float*)d_in[9];
    float* out = (float*)d_out;

    // ws layout (MFMA path): Z0x 8MB | yy 2MB | Whi 8MB | Wlo 8MB | yhi 1MB | ylo 1MB
    const size_t Z0X_B = (size_t)8 * 1024 * 1024;
    const size_t YY_B  = (size_t)2 * 1024 * 1024;
    const size_t WSP_B = (size_t)8000 * 512 * 2;        // 8,192,000
    const size_t YSP_B = (size_t)1024 * 512 * 2;        // 1,048,576
    const size_t NEED  = Z0X_B + YY_B + 2 * WSP_B + 2 * YSP_B + 4096;

    char* ws = (char*)d_ws;

    if (ws_size >= NEED) {
        float*     Z0x = (float*)ws;
        float*     yy  = (float*)(ws + Z0X_B);
        _Float16*  Whi = (_Float16*)(ws + Z0X_B + YY_B);
        _Float16*  Wlo = (_Float16*)(ws + Z0X_B + YY_B + WSP_B);
        _Float16*  yhi = (_Float16*)(ws + Z0X_B + YY_B + 2 * WSP_B);
        _Float16*  ylo = (_Float16*)(ws + Z0X_B + YY_B + 2 * WSP_B + YSP_B);

        k_prep<<<2512, 256, 0, stream>>>(inputs, emb, W0, b0, Z0x, Wd, Whi, Wlo);
        k_lstm_m<<<4, 256, 0, stream>>>(Z0x, U0, W1, U1, b1, yy);
        k_ysplit<<<256, 256, 0, stream>>>(yy, yhi, ylo);
        k_dense_mfma<<<dim3(64, 100), 256, 0, stream>>>(yhi, ylo, Whi, Wlo, bd, out);
    } else {
        // small-ws fallback: Z0x in d_out tail, yy in ws, fp32 dense
        float* yy = (float*)ws;
        size_t out_bytes = (size_t)out_size * sizeof(float);
        float* Z0x = (float*)((char*)d_out + out_bytes - Z0X_B);

        k_prep<<<2512, 256, 0, stream>>>(inputs, emb, W0, b0, Z0x,
                                         Wd, nullptr, nullptr);
        k_lstm_m<<<4, 256, 0, stream>>>(Z0x, U0, W1, U1, b1, yy);
        k_dense<<<dim3(64, 250), 256, 0, stream>>>(yy, Wd, bd, out);
    }
}